// Round 15
// baseline (113.916 us; speedup 1.0000x reference)
//
#include <hip/hip_runtime.h>
#include <hip/hip_bf16.h>
#include <stdint.h>

typedef __bf16 bf16_t;
typedef __bf16 bf16x8 __attribute__((ext_vector_type(8)));
typedef __bf16 bf16x4 __attribute__((ext_vector_type(4)));
typedef float  f32x4  __attribute__((ext_vector_type(4)));
typedef float  f32x16 __attribute__((ext_vector_type(16)));

#define DIM   1024
#define BATCH 8
#define SCALE 0.03125f        /* 1/sqrt(1024) */

// Algebra: out[z,i,n] = v + SCALE*scores
//   scores = x M x^T + (x u)1^T + 1(w2^T x^T) + c,  M = Wq^T Weff Wk
//   MT = (Wk^T Weff^T) Wq; t_s = x MT^T; out = t_s x^T + x Wv^T + RU + RW + bv

// ---------------- wave row-dot helper ----------------
__device__ __forceinline__ float rowdot_bf16(const bf16_t* __restrict__ row,
                                             const float* __restrict__ vec, int lane) {
    float s = 0.f;
#pragma unroll
    for (int c = 0; c < 2; ++c) {
        const int d0 = (lane + c * 64) * 8;
        const bf16x8 v = *reinterpret_cast<const bf16x8*>(row + d0);
#pragma unroll
        for (int e = 0; e < 8; ++e) s += vec[d0 + e] * (float)v[e];
    }
#pragma unroll
    for (int off = 32; off; off >>= 1) s += __shfl_down(s, off);
    return s;
}

// ------------- split-K 128x128 GEMM body (R12 proven, verbatim) -------------
__device__ __forceinline__ void gemm_sk(const bf16_t* __restrict__ A, const bf16_t* __restrict__ B,
                                        float* __restrict__ oP, int s, int tid,
                                        bf16_t* As, bf16_t* Bs)
{
    const int wave = tid >> 6, lane = tid & 63;
    const int bm = (s >> 5) * 128;
    const int bn = ((s >> 2) & 7) * 128;
    const int kb = (s & 3) * 256;
    float* outP  = oP + (long)(s & 3) * 1048576;
    const int wr = wave >> 1, wc = wave & 1;
    const int lhi = lane >> 4, llo = lane & 15;

    f32x4 acc[4][4];
    const f32x4 fz = {0.f, 0.f, 0.f, 0.f};
#pragma unroll
    for (int i = 0; i < 4; ++i)
#pragma unroll
        for (int j = 0; j < 4; ++j) acc[i][j] = fz;

    for (int k0 = 0; k0 < 256; k0 += 32) {
#pragma unroll
        for (int i = 0; i < 2; ++i) {
            const int c  = wave * 128 + i * 64 + lane;
            const int r  = c >> 2;
            const int cc = (c & 3) << 3;
            const long ga = (long)(bm + r) * 1024 + kb + k0 + cc;
            const long gb = (long)(bn + r) * 1024 + kb + k0 + cc;
            const int lbase = (wave * 128 + i * 64) << 3;
            __builtin_amdgcn_global_load_lds(
                (const __attribute__((address_space(1))) uint32_t*)(A + ga),
                (__attribute__((address_space(3))) uint32_t*)(&As[lbase]), 16, 0, 0);
            __builtin_amdgcn_global_load_lds(
                (const __attribute__((address_space(1))) uint32_t*)(B + gb),
                (__attribute__((address_space(3))) uint32_t*)(&Bs[lbase]), 16, 0, 0);
        }
        __syncthreads();

        bf16x8 af[4], bfr[4];
#pragma unroll
        for (int mi = 0; mi < 4; ++mi)
            af[mi] = *reinterpret_cast<const bf16x8*>(&As[(wr * 64 + mi * 16 + llo) * 32 + lhi * 8]);
#pragma unroll
        for (int ni = 0; ni < 4; ++ni)
            bfr[ni] = *reinterpret_cast<const bf16x8*>(&Bs[(wc * 64 + ni * 16 + llo) * 32 + lhi * 8]);
#pragma unroll
        for (int mi = 0; mi < 4; ++mi)
#pragma unroll
            for (int ni = 0; ni < 4; ++ni)
                acc[mi][ni] = __builtin_amdgcn_mfma_f32_16x16x32_bf16(af[mi], bfr[ni], acc[mi][ni], 0, 0, 0);
        __syncthreads();
    }

#pragma unroll
    for (int mi = 0; mi < 4; ++mi) {
        const int r0 = bm + wr * 64 + mi * 16 + lhi * 4;
#pragma unroll
        for (int ni = 0; ni < 4; ++ni) {
            const int cg = bn + wc * 64 + ni * 16 + llo;
            const f32x4 v = acc[mi][ni];
#pragma unroll
            for (int j = 0; j < 4; ++j)
                outP[(long)(r0 + j) * 1024 + cg] = v[j];
        }
    }
}

// ============== K1: fused preamble ==============
__global__ __launch_bounds__(256)
void k_prep(const float* __restrict__ x, const float* __restrict__ Wqkv,
            const float* __restrict__ w,
            bf16_t* __restrict__ xb, bf16_t* __restrict__ wvb,
            bf16_t* __restrict__ weff, bf16_t* __restrict__ wtb,
            bf16_t* __restrict__ wqt, bf16_t* __restrict__ wkt)
{
    __shared__ float tile[32][33];
    const int b = blockIdx.x;
    if (b < 8192) {
        const int i = b * 256 + threadIdx.x;
        const float4 v = reinterpret_cast<const float4*>(x)[i];
        bf16x4 o;
        o.x = (bf16_t)v.x; o.y = (bf16_t)v.y; o.z = (bf16_t)v.z; o.w = (bf16_t)v.w;
        reinterpret_cast<bf16x4*>(xb)[i] = o;
    } else if (b < 9216) {
        const int i = (b - 8192) * 256 + threadIdx.x;
        const float4 v = reinterpret_cast<const float4*>(Wqkv + 2097152)[i];
        bf16x4 o;
        o.x = (bf16_t)v.x; o.y = (bf16_t)v.y; o.z = (bf16_t)v.z; o.w = (bf16_t)v.w;
        reinterpret_cast<bf16x4*>(wvb)[i] = o;
    } else if (b < 10240) {
        const int t  = b - 9216;
        const int tx = threadIdx.x & 31, ty = threadIdx.x >> 5;
        const int d0 = (t & 31) * 32, e0 = (t >> 5) * 32;
#pragma unroll
        for (int r = 0; r < 4; ++r) {
            const int d = d0 + r * 8 + ty;
            const int e = e0 + tx;
            const float sum =
                w[d * 1024 + e] + w[1048576 + d * 1024 + e] + w[2097152 + d * 1024 + e];
            tile[r * 8 + ty][tx] = sum;
            weff[(long)d * 1024 + e] = (bf16_t)sum;
        }
        __syncthreads();
#pragma unroll
        for (int r = 0; r < 4; ++r) {
            const int e = e0 + r * 8 + ty;
            const int d = d0 + tx;
            wtb[(long)e * 1024 + d] = (bf16_t)tile[tx][r * 8 + ty];
        }
    } else {
        const bool isQ = (b < 11264);
        const int t  = b - (isQ ? 10240 : 11264);
        const float* src = isQ ? Wqkv : (Wqkv + 1048576);
        bf16_t* dst = isQ ? wqt : wkt;
        const int tx = threadIdx.x & 31, ty = threadIdx.x >> 5;
        const int e0 = (t & 31) * 32, d0 = (t >> 5) * 32;
#pragma unroll
        for (int r = 0; r < 4; ++r)
            tile[r * 8 + ty][tx] = src[(long)(e0 + r * 8 + ty) * 1024 + d0 + tx];
        __syncthreads();
#pragma unroll
        for (int r = 0; r < 4; ++r)
            dst[(long)(d0 + r * 8 + ty) * 1024 + e0 + tx] = (bf16_t)tile[tx][r * 8 + ty];
    }
}

// ====== K2a: X1 = Wk^T Weff^T (split-K) ∪ h1,h2 row-dots ======
__global__ __launch_bounds__(256)
void k_midA(const bf16_t* __restrict__ wkt, const bf16_t* __restrict__ weff,
            const bf16_t* __restrict__ wtb, const float* __restrict__ bqkv,
            float* __restrict__ pX1, float* __restrict__ h1, float* __restrict__ h2)
{
    __shared__ __align__(16) bf16_t As[128 * 32];
    __shared__ __align__(16) bf16_t Bs[128 * 32];
    if (blockIdx.x < 256) {
        gemm_sk(wkt, weff, pX1, blockIdx.x, threadIdx.x, As, Bs);
        return;
    }
    const int wave = threadIdx.x >> 6, lane = threadIdx.x & 63;
    const int r = ((int)blockIdx.x - 256) * 4 + wave;
    if (r < 1024) {
        const float s = rowdot_bf16(weff + (long)r * 1024, bqkv + 1024, lane);
        if (lane == 0) h1[r] = s;
    } else {
        const float s = rowdot_bf16(wtb + (long)(r - 1024) * 1024, bqkv, lane);
        if (lane == 0) h2[r - 1024] = s;
    }
}

// ====== K2b: X1b = bf16(sum4 partials) ∪ u,w2 row-dots ∪ c ======
__global__ __launch_bounds__(256)
void k_cvtA(const float* __restrict__ p, bf16_t* __restrict__ X1b,
            const bf16_t* __restrict__ wqt, const bf16_t* __restrict__ wkt,
            const float* __restrict__ h1, const float* __restrict__ h2,
            const float* __restrict__ bqkv,
            float* __restrict__ u, float* __restrict__ w2, float* __restrict__ cO)
{
    const int b = blockIdx.x;
    if (b < 1024) {
        const int i = b * 256 + threadIdx.x;
        const f32x4* rp = reinterpret_cast<const f32x4*>(p);
        const f32x4 a0 = rp[i], a1 = rp[i + 262144], a2 = rp[i + 524288], a3 = rp[i + 786432];
        bf16x4 o;
        o.x = (bf16_t)(a0.x + a1.x + a2.x + a3.x);
        o.y = (bf16_t)(a0.y + a1.y + a2.y + a3.y);
        o.z = (bf16_t)(a0.z + a1.z + a2.z + a3.z);
        o.w = (bf16_t)(a0.w + a1.w + a2.w + a3.w);
        reinterpret_cast<bf16x4*>(X1b)[i] = o;
    } else if (b < 1536) {
        const int wave = threadIdx.x >> 6, lane = threadIdx.x & 63;
        const int rr = (b - 1024) * 4 + wave;
        if (rr < 1024) {
            const float s = rowdot_bf16(wqt + (long)rr * 1024, h1, lane);
            if (lane == 0) u[rr] = s;
        } else {
            const float s = rowdot_bf16(wkt + (long)(rr - 1024) * 1024, h2, lane);
            if (lane == 0) w2[rr - 1024] = s;
        }
    } else {
        if (threadIdx.x < 64) {
            float s = 0.f;
            for (int i = threadIdx.x; i < 1024; i += 64) s += bqkv[i] * h1[i];
#pragma unroll
            for (int off = 32; off; off >>= 1) s += __shfl_down(s, off);
            if (threadIdx.x == 0) cO[0] = s;
        }
    }
}

// ====== K2c: MT = X1b Wq-contract (split-K) ∪ RU/RW dual GEMV over xb ======
__global__ __launch_bounds__(256)
void k_midB(const bf16_t* __restrict__ X1b, const bf16_t* __restrict__ wqt,
            float* __restrict__ pMT, const bf16_t* __restrict__ xb,
            const float* __restrict__ u, const float* __restrict__ w2,
            const float* __restrict__ cO,
            float* __restrict__ RU, float* __restrict__ RW)
{
    __shared__ __align__(16) bf16_t As[128 * 32];
    __shared__ __align__(16) bf16_t Bs[128 * 32];
    if (blockIdx.x < 256) {
        gemm_sk(X1b, wqt, pMT, blockIdx.x, threadIdx.x, As, Bs);
        return;
    }
    const int wave = threadIdx.x >> 6, lane = threadIdx.x & 63;
    const int s = ((int)blockIdx.x - 256) * 4 + wave;
    const bf16_t* row = xb + (long)s * 1024;
    float s1 = 0.f, s2 = 0.f;
#pragma unroll
    for (int c = 0; c < 2; ++c) {
        const int d0 = (lane + c * 64) * 8;
        const bf16x8 v = *reinterpret_cast<const bf16x8*>(row + d0);
#pragma unroll
        for (int e = 0; e < 8; ++e) {
            const float f = (float)v[e];
            s1 += u[d0 + e] * f;
            s2 += w2[d0 + e] * f;
        }
    }
#pragma unroll
    for (int off = 32; off; off >>= 1) { s1 += __shfl_down(s1, off); s2 += __shfl_down(s2, off); }
    if (lane == 0) {
        RU[s] = SCALE * (s1 + cO[0]);
        RW[s] = SCALE * s2;
    }
}

// ---------------- K2d: MTb = bf16( SCALE * sum of 4 partials ) ----------------
__global__ __launch_bounds__(256)
void k_cvtS(const float* __restrict__ p, bf16_t* __restrict__ out) {
    const int i = blockIdx.x * 256 + threadIdx.x;
    const f32x4* rp = reinterpret_cast<const f32x4*>(p);
    const f32x4 a0 = rp[i], a1 = rp[i + 262144], a2 = rp[i + 524288], a3 = rp[i + 786432];
    bf16x4 o;
    o.x = (bf16_t)(SCALE * (a0.x + a1.x + a2.x + a3.x));
    o.y = (bf16_t)(SCALE * (a0.y + a1.y + a2.y + a3.y));
    o.z = (bf16_t)(SCALE * (a0.z + a1.z + a2.z + a3.z));
    o.w = (bf16_t)(SCALE * (a0.w + a1.w + a2.w + a3.w));
    reinterpret_cast<bf16x4*>(out)[i] = o;
}

// ========== main GEMM: 32x32x16 MFMA, 4 waves, 128x128 tile, BK=64 dbuf ==========
// Per-wave 64x64 = 2x2 mfma_f32_32x32x16_bf16 frags: 16 MFMA + 16 ds_read_b128
// per K-tile (21.9 FLOP/LDS-byte vs 16.4 for the 16x16 path). LDS 2x32KB = 64KB
// -> 2 blocks/CU. Sync cadence identical to proven R12: {stage(t+1); vmcnt(8);
// barrier; 16 reads; 16 MFMA; lgkmcnt(0); barrier}.
// Swizzle: phys chunk = logical ^ f(r), f(r) = (r&7)^((r>>3)&3) (involution);
// staged linearly from inverse-swizzled global source.
// Fragment layouts (gfx950): A/B row|col = lane&31, k = (lane>>5)*8 + j;
// C/D col = lane&31, row = (reg&3) + 8*(reg>>2) + 4*(lane>>5)  [m74/m101].
// MODE 0: t_s = xb @ MTb^T (NTT=16, bf16 out, m-grouped XCD chunks)
// MODE 1: out[z] = t_s[z]@xb[z]^T + xb[z]@wvb^T + RU + RW + bv (NTT=32, XCD=batch)
#define GLOAD(SRC, DST) __builtin_amdgcn_global_load_lds( \
    (const __attribute__((address_space(1))) uint32_t*)(SRC), \
    (__attribute__((address_space(3))) uint32_t*)(DST), 16, 0, 0)

__device__ __forceinline__ int fswz(int r) { return (r & 7) ^ ((r >> 3) & 3); }

template<int MODE>
__global__ __launch_bounds__(256, 2)
void k_mm32(const bf16_t* __restrict__ A1, const bf16_t* __restrict__ A2,
            const bf16_t* __restrict__ B1, const bf16_t* __restrict__ B2,
            const float* __restrict__ RUv, const float* __restrict__ RWv,
            const float* __restrict__ bv,
            bf16_t* __restrict__ oT, float* __restrict__ oF)
{
    constexpr int SLOT = 32768;             // A 16KB + B 16KB
    constexpr int NTT  = (MODE == 0) ? 16 : 32;
    __shared__ __align__(16) unsigned char slds[2 * SLOT];

    const int tid  = threadIdx.x;
    const int wave = tid >> 6, lane = tid & 63;
    const int wmm = wave >> 1, wnn = wave & 1;
    const int lr = lane & 31, lk = lane >> 5;

    int bm, bn, z = 0;
    const int nw = ((int)blockIdx.x & 7) * 64 + ((int)blockIdx.x >> 3);
    if (MODE == 0) {
        bm = (nw >> 3) * 128;               // m-grouped: XCD c -> m-panels [8c,8c+8)
        bn = (nw & 7) * 128;
    } else {
        z = nw >> 6;                        // batch = XCD
        const int r = nw & 63;
        bm = (r >> 3) * 128; bn = (r & 7) * 128;
    }
    const long zo = (long)z << 20;

    // per-thread staging: 8 chunks/tile (j<4 -> A rows, j>=4 -> B rows)
    const bf16_t *s1[8], *s2[8]; int dst[8];
#pragma unroll
    for (int j = 0; j < 8; ++j) {
        const int C = (j & 3) * 256 + tid;  // 0..1023 within A or B region
        const int r = C >> 3;
        const int u = (C & 7) ^ fswz(r);
        if (j < 4) {
            const long off = (long)(bm + r) * 1024 + (u << 3);
            s1[j] = A1 + zo + off;
            s2[j] = (MODE == 1) ? (A2 + zo + off) : nullptr;
            dst[j] = C << 4;
        } else {
            const long off = (long)(bn + r) * 1024 + (u << 3);
            s1[j] = B1 + ((MODE == 1) ? zo : 0) + off;
            s2[j] = (MODE == 1) ? (B2 + off) : nullptr;   // wvb: no batch offset
            dst[j] = 16384 + (C << 4);
        }
    }

    auto stage = [&](int tt) {
        unsigned char* s = &slds[(tt & 1) * SLOT];
        const long ko = (long)(tt & 15) << 6;
        const bool hB = (MODE == 1) && (tt >= 16);
#pragma unroll
        for (int j = 0; j < 8; ++j)
            GLOAD((hB ? s2[j] : s1[j]) + ko, s + dst[j]);
    };

    f32x16 acc[2][2];
#pragma unroll
    for (int i = 0; i < 2; ++i)
#pragma unroll
        for (int j = 0; j < 2; ++j)
#pragma unroll
            for (int q = 0; q < 16; ++q) acc[i][j][q] = 0.f;

    stage(0);

    for (int t = 0; t < NTT; ++t) {
        if (t + 1 < NTT) {
            stage(t + 1);
            asm volatile("s_waitcnt vmcnt(8)" ::: "memory");
        } else {
            asm volatile("s_waitcnt vmcnt(0)" ::: "memory");
        }
        __builtin_amdgcn_s_barrier();

        const unsigned char* sb = &slds[(t & 1) * SLOT];
        bf16x8 af[2][4], bf[2][4];
#pragma unroll
        for (int mb = 0; mb < 2; ++mb) {
            const int r = wmm * 64 + mb * 32 + lr;
            const int f = fswz(r);
#pragma unroll
            for (int s = 0; s < 4; ++s)
                af[mb][s] = *reinterpret_cast<const bf16x8*>(
                    sb + r * 128 + ((((s << 1) | lk) ^ f) << 4));
        }
#pragma unroll
        for (int nb = 0; nb < 2; ++nb) {
            const int r = wnn * 64 + nb * 32 + lr;
            const int f = fswz(r);
#pragma unroll
            for (int s = 0; s < 4; ++s)
                bf[nb][s] = *reinterpret_cast<const bf16x8*>(
                    sb + 16384 + r * 128 + ((((s << 1) | lk) ^ f) << 4));
        }
        __builtin_amdgcn_s_setprio(1);
#pragma unroll
        for (int s = 0; s < 4; ++s)
#pragma unroll
            for (int mb = 0; mb < 2; ++mb)
#pragma unroll
                for (int nb = 0; nb < 2; ++nb)
                    acc[mb][nb] = __builtin_amdgcn_mfma_f32_32x32x16_bf16(
                        af[mb][s], bf[nb][s], acc[mb][nb], 0, 0, 0);
        __builtin_amdgcn_s_setprio(0);
        asm volatile("s_waitcnt lgkmcnt(0)" ::: "memory");
        __builtin_amdgcn_s_barrier();
    }

    // ---------------- epilogue (C/D: col=lane&31, row=(reg&3)+8*(reg>>2)+4*lk) ----
#pragma unroll
    for (int mb = 0; mb < 2; ++mb) {
#pragma unroll
        for (int nb = 0; nb < 2; ++nb) {
            const int cg = bn + wnn * 64 + nb * 32 + lr;
            const float cterm = (MODE == 1) ? (RWv[z * 1024 + cg] + bv[cg]) : 0.f;
#pragma unroll
            for (int g = 0; g < 4; ++g) {
                const int r0 = bm + wmm * 64 + mb * 32 + g * 8 + lk * 4;
#pragma unroll
                for (int q = 0; q < 4; ++q) {
                    const float val = acc[mb][nb][g * 4 + q];
                    if (MODE == 0) {
                        oT[(long)(r0 + q) * 1024 + cg] = (bf16_t)val;
                    } else {
                        oF[zo + (long)(r0 + q) * 1024 + cg] =
                            val + RUv[z * 1024 + r0 + q] + cterm;
                    }
                }
            }
        }
    }
}
#undef GLOAD

extern "C" void kernel_launch(void* const* d_in, const int* in_sizes, int n_in,
                              void* d_out, int out_size, void* d_ws, size_t ws_size,
                              hipStream_t stream) {
    const float* x    = (const float*)d_in[0];
    const float* Wqkv = (const float*)d_in[1];
    const float* bqkv = (const float*)d_in[2];
    const float* w    = (const float*)d_in[3];
    float* out = (float*)d_out;

    // workspace layout
    char* ws = (char*)d_ws;
    bf16_t* xb   = (bf16_t*)ws;                       // 16 MiB
    float*  pbig = (float*) (ws + (16l << 20));       // 16 MiB partials
    bf16_t* tsb  = (bf16_t*)(ws + (16l << 20));       // 16 MiB t_s (after partials dead)
    bf16_t* weff = (bf16_t*)(ws + (32l << 20));       // 2 MiB
    bf16_t* wtb  = (bf16_t*)(ws + (34l << 20));       // 2 MiB
    bf16_t* wqt  = (bf16_t*)(ws + (36l << 20));       // 2 MiB
    bf16_t* wkt  = (bf16_t*)(ws + (38l << 20));       // 2 MiB
    bf16_t* wvb  = (bf16_t*)(ws + (40l << 20));       // 2 MiB
    bf16_t* X1b  = (bf16_t*)(ws + (42l << 20));       // 2 MiB
    bf16_t* MTb  = (bf16_t*)(ws + (44l << 20));       // 2 MiB
    char*   sm   = ws + (46l << 20);
    float* h1 = (float*)sm;
    float* h2 = (float*)(sm + 4096);
    float* u  = (float*)(sm + 8192);
    float* w2 = (float*)(sm + 12288);
    float* cO = (float*)(sm + 16384);
    float* RU = (float*)(sm + 20480);
    float* RW = (float*)(sm + 53248);
    if (ws_size < (size_t)(54l << 20) + 65536) return;

    // K1: preamble
    k_prep<<<12288, 256, 0, stream>>>(x, Wqkv, w, xb, wvb, weff, wtb, wqt, wkt);

    // K2a: X1 = Wk^T Weff^T + h1,h2
    k_midA<<<768, 256, 0, stream>>>(wkt, weff, wtb, bqkv, pbig, h1, h2);

    // K2b: X1b = bf16(sum partials) + u,w2 + c
    k_cvtA<<<1537, 256, 0, stream>>>(pbig, X1b, wqt, wkt, h1, h2, bqkv, u, w2, cO);

    // K2c: MT = X1b Wq + RU/RW GEMVs
    k_midB<<<2304, 256, 0, stream>>>(X1b, wqt, pbig, xb, u, w2, cO, RU, RW);

    // K2d: MTb = bf16(SCALE * sum partials)
    k_cvtS<<<1024, 256, 0, stream>>>(pbig, MTb);

    // t_s = xb @ MTb^T  (512 blocks, m-grouped XCD chunks)
    k_mm32<0><<<512, 256, 0, stream>>>(xb, nullptr, MTb, nullptr,
                                       nullptr, nullptr, nullptr, tsb, nullptr);

    // out = t_s@x^T + x@Wv^T + RU + RW + bv  (512 blocks, XCD = batch)
    k_mm32<1><<<512, 256, 0, stream>>>(tsb, xb, xb, wvb,
                                       RU, RW, bqkv + 2048, nullptr, out);
}

// Round 16
// 108.219 us; speedup vs baseline: 1.0526x; 1.0526x over previous
//
#include <hip/hip_runtime.h>
#include <hip/hip_bf16.h>
#include <stdint.h>

typedef __bf16 bf16_t;
typedef __bf16 bf16x8 __attribute__((ext_vector_type(8)));
typedef __bf16 bf16x4 __attribute__((ext_vector_type(4)));
typedef float  f32x4  __attribute__((ext_vector_type(4)));

#define DIM   1024
#define BATCH 8
#define SCALE 0.03125f        /* 1/sqrt(1024) */

// Algebra: out[z,i,n] = v[z,i,n] + SCALE*scores[z,i,n]
//   scores = x M x^T + (x u)1^T + 1(w2^T x^T) + c,  M = Wq^T Weff Wk
//   v = x Wv^T + bv
// Computed as:
//   MT = M^T = (Wk^T Weff^T) Wq  (two 1024^3 split-K GEMMs, SCALE folded at cvt)
//   t_s = x MT^T (bf16)                                  [k_db2<0>]
//   out = t_s x^T + x Wv^T + RU[row] + RW[col] + bv[col] [k_db2<1>, K=2048]
//   RU[s] = SCALE*(x·u + c), RW[s] = SCALE*(x·w2)
//   u = wqt·h1, w2 = wkt·h2, h1 = weff·bk, h2 = wtb·bq, c = bq·h1

// ---------------- wave row-dot helper ----------------
__device__ __forceinline__ float rowdot_bf16(const bf16_t* __restrict__ row,
                                             const float* __restrict__ vec, int lane) {
    float s = 0.f;
#pragma unroll
    for (int c = 0; c < 2; ++c) {
        const int d0 = (lane + c * 64) * 8;
        const bf16x8 v = *reinterpret_cast<const bf16x8*>(row + d0);
#pragma unroll
        for (int e = 0; e < 8; ++e) s += vec[d0 + e] * (float)v[e];
    }
#pragma unroll
    for (int off = 32; off; off >>= 1) s += __shfl_down(s, off);
    return s;   // valid in lane 0
}

// ------------- split-K 128x128 GEMM body (R12 proven, verbatim) -------------
__device__ __forceinline__ void gemm_sk(const bf16_t* __restrict__ A, const bf16_t* __restrict__ B,
                                        float* __restrict__ oP, int s, int tid,
                                        bf16_t* As, bf16_t* Bs)
{
    const int wave = tid >> 6, lane = tid & 63;
    const int bm = (s >> 5) * 128;
    const int bn = ((s >> 2) & 7) * 128;
    const int kb = (s & 3) * 256;
    float* outP  = oP + (long)(s & 3) * 1048576;
    const int wr = wave >> 1, wc = wave & 1;
    const int lhi = lane >> 4, llo = lane & 15;

    f32x4 acc[4][4];
    const f32x4 fz = {0.f, 0.f, 0.f, 0.f};
#pragma unroll
    for (int i = 0; i < 4; ++i)
#pragma unroll
        for (int j = 0; j < 4; ++j) acc[i][j] = fz;

    for (int k0 = 0; k0 < 256; k0 += 32) {
#pragma unroll
        for (int i = 0; i < 2; ++i) {
            const int c  = wave * 128 + i * 64 + lane;
            const int r  = c >> 2;
            const int cc = (c & 3) << 3;
            const long ga = (long)(bm + r) * 1024 + kb + k0 + cc;
            const long gb = (long)(bn + r) * 1024 + kb + k0 + cc;
            const int lbase = (wave * 128 + i * 64) << 3;
            __builtin_amdgcn_global_load_lds(
                (const __attribute__((address_space(1))) uint32_t*)(A + ga),
                (__attribute__((address_space(3))) uint32_t*)(&As[lbase]), 16, 0, 0);
            __builtin_amdgcn_global_load_lds(
                (const __attribute__((address_space(1))) uint32_t*)(B + gb),
                (__attribute__((address_space(3))) uint32_t*)(&Bs[lbase]), 16, 0, 0);
        }
        __syncthreads();

        bf16x8 af[4], bfr[4];
#pragma unroll
        for (int mi = 0; mi < 4; ++mi)
            af[mi] = *reinterpret_cast<const bf16x8*>(&As[(wr * 64 + mi * 16 + llo) * 32 + lhi * 8]);
#pragma unroll
        for (int ni = 0; ni < 4; ++ni)
            bfr[ni] = *reinterpret_cast<const bf16x8*>(&Bs[(wc * 64 + ni * 16 + llo) * 32 + lhi * 8]);
#pragma unroll
        for (int mi = 0; mi < 4; ++mi)
#pragma unroll
            for (int ni = 0; ni < 4; ++ni)
                acc[mi][ni] = __builtin_amdgcn_mfma_f32_16x16x32_bf16(af[mi], bfr[ni], acc[mi][ni], 0, 0, 0);
        __syncthreads();
    }

#pragma unroll
    for (int mi = 0; mi < 4; ++mi) {
        const int r0 = bm + wr * 64 + mi * 16 + lhi * 4;
#pragma unroll
        for (int ni = 0; ni < 4; ++ni) {
            const int cg = bn + wc * 64 + ni * 16 + llo;
            const f32x4 v = acc[mi][ni];
#pragma unroll
            for (int j = 0; j < 4; ++j)
                outP[(long)(r0 + j) * 1024 + cg] = v[j];
        }
    }
}

// ============== K1: fused preamble ==============
__global__ __launch_bounds__(256)
void k_prep(const float* __restrict__ x, const float* __restrict__ Wqkv,
            const float* __restrict__ w,
            bf16_t* __restrict__ xb, bf16_t* __restrict__ wvb,
            bf16_t* __restrict__ weff, bf16_t* __restrict__ wtb,
            bf16_t* __restrict__ wqt, bf16_t* __restrict__ wkt)
{
    __shared__ float tile[32][33];
    const int b = blockIdx.x;
    if (b < 8192) {
        const int i = b * 256 + threadIdx.x;
        const float4 v = reinterpret_cast<const float4*>(x)[i];
        bf16x4 o;
        o.x = (bf16_t)v.x; o.y = (bf16_t)v.y; o.z = (bf16_t)v.z; o.w = (bf16_t)v.w;
        reinterpret_cast<bf16x4*>(xb)[i] = o;
    } else if (b < 9216) {
        const int i = (b - 8192) * 256 + threadIdx.x;
        const float4 v = reinterpret_cast<const float4*>(Wqkv + 2097152)[i];
        bf16x4 o;
        o.x = (bf16_t)v.x; o.y = (bf16_t)v.y; o.z = (bf16_t)v.z; o.w = (bf16_t)v.w;
        reinterpret_cast<bf16x4*>(wvb)[i] = o;
    } else if (b < 10240) {
        const int t  = b - 9216;
        const int tx = threadIdx.x & 31, ty = threadIdx.x >> 5;
        const int d0 = (t & 31) * 32, e0 = (t >> 5) * 32;
#pragma unroll
        for (int r = 0; r < 4; ++r) {
            const int d = d0 + r * 8 + ty;
            const int e = e0 + tx;
            const float sum =
                w[d * 1024 + e] + w[1048576 + d * 1024 + e] + w[2097152 + d * 1024 + e];
            tile[r * 8 + ty][tx] = sum;
            weff[(long)d * 1024 + e] = (bf16_t)sum;
        }
        __syncthreads();
#pragma unroll
        for (int r = 0; r < 4; ++r) {
            const int e = e0 + r * 8 + ty;
            const int d = d0 + tx;
            wtb[(long)e * 1024 + d] = (bf16_t)tile[tx][r * 8 + ty];
        }
    } else {
        const bool isQ = (b < 11264);
        const int t  = b - (isQ ? 10240 : 11264);
        const float* src = isQ ? Wqkv : (Wqkv + 1048576);
        bf16_t* dst = isQ ? wqt : wkt;
        const int tx = threadIdx.x & 31, ty = threadIdx.x >> 5;
        const int e0 = (t & 31) * 32, d0 = (t >> 5) * 32;
#pragma unroll
        for (int r = 0; r < 4; ++r)
            tile[r * 8 + ty][tx] = src[(long)(e0 + r * 8 + ty) * 1024 + d0 + tx];
        __syncthreads();
#pragma unroll
        for (int r = 0; r < 4; ++r)
            dst[(long)(d0 + r * 8 + ty) * 1024 + e0 + tx] = (bf16_t)tile[tx][r * 8 + ty];
    }
}

// ====== K2a: X1 = Wk^T Weff^T (split-K) ∪ h1,h2 row-dots ======
__global__ __launch_bounds__(256)
void k_midA(const bf16_t* __restrict__ wkt, const bf16_t* __restrict__ weff,
            const bf16_t* __restrict__ wtb, const float* __restrict__ bqkv,
            float* __restrict__ pX1, float* __restrict__ h1, float* __restrict__ h2)
{
    __shared__ __align__(16) bf16_t As[128 * 32];
    __shared__ __align__(16) bf16_t Bs[128 * 32];
    if (blockIdx.x < 256) {
        gemm_sk(wkt, weff, pX1, blockIdx.x, threadIdx.x, As, Bs);
        return;
    }
    const int wave = threadIdx.x >> 6, lane = threadIdx.x & 63;
    const int r = ((int)blockIdx.x - 256) * 4 + wave;    // 0..2047
    if (r < 1024) {
        const float s = rowdot_bf16(weff + (long)r * 1024, bqkv + 1024, lane);  // h1 = Weff*bk
        if (lane == 0) h1[r] = s;
    } else {
        const float s = rowdot_bf16(wtb + (long)(r - 1024) * 1024, bqkv, lane); // h2 = Weff^T*bq
        if (lane == 0) h2[r - 1024] = s;
    }
}

// ====== K2b: X1b = bf16(sum4 partials) ∪ u,w2 row-dots ∪ c ======
__global__ __launch_bounds__(256)
void k_cvtA(const float* __restrict__ p, bf16_t* __restrict__ X1b,
            const bf16_t* __restrict__ wqt, const bf16_t* __restrict__ wkt,
            const float* __restrict__ h1, const float* __restrict__ h2,
            const float* __restrict__ bqkv,
            float* __restrict__ u, float* __restrict__ w2, float* __restrict__ cO)
{
    const int b = blockIdx.x;
    if (b < 1024) {
        const int i = b * 256 + threadIdx.x;
        const f32x4* rp = reinterpret_cast<const f32x4*>(p);
        const f32x4 a0 = rp[i], a1 = rp[i + 262144], a2 = rp[i + 524288], a3 = rp[i + 786432];
        bf16x4 o;
        o.x = (bf16_t)(a0.x + a1.x + a2.x + a3.x);
        o.y = (bf16_t)(a0.y + a1.y + a2.y + a3.y);
        o.z = (bf16_t)(a0.z + a1.z + a2.z + a3.z);
        o.w = (bf16_t)(a0.w + a1.w + a2.w + a3.w);
        reinterpret_cast<bf16x4*>(X1b)[i] = o;
    } else if (b < 1536) {
        const int wave = threadIdx.x >> 6, lane = threadIdx.x & 63;
        const int rr = (b - 1024) * 4 + wave;            // 0..2047
        if (rr < 1024) {
            const float s = rowdot_bf16(wqt + (long)rr * 1024, h1, lane);        // u = wqt*h1
            if (lane == 0) u[rr] = s;
        } else {
            const float s = rowdot_bf16(wkt + (long)(rr - 1024) * 1024, h2, lane); // w2 = wkt*h2
            if (lane == 0) w2[rr - 1024] = s;
        }
    } else {
        if (threadIdx.x < 64) {
            float s = 0.f;
            for (int i = threadIdx.x; i < 1024; i += 64) s += bqkv[i] * h1[i];
#pragma unroll
            for (int off = 32; off; off >>= 1) s += __shfl_down(s, off);
            if (threadIdx.x == 0) cO[0] = s;             // c = bq . h1
        }
    }
}

// ====== K2c: MT = X1b Wq-contract (split-K) ∪ RU/RW dual GEMV over xb ======
__global__ __launch_bounds__(256)
void k_midB(const bf16_t* __restrict__ X1b, const bf16_t* __restrict__ wqt,
            float* __restrict__ pMT, const bf16_t* __restrict__ xb,
            const float* __restrict__ u, const float* __restrict__ w2,
            const float* __restrict__ cO,
            float* __restrict__ RU, float* __restrict__ RW)
{
    __shared__ __align__(16) bf16_t As[128 * 32];
    __shared__ __align__(16) bf16_t Bs[128 * 32];
    if (blockIdx.x < 256) {
        gemm_sk(X1b, wqt, pMT, blockIdx.x, threadIdx.x, As, Bs);
        return;
    }
    const int wave = threadIdx.x >> 6, lane = threadIdx.x & 63;
    const int s = ((int)blockIdx.x - 256) * 4 + wave;    // 0..8191
    const bf16_t* row = xb + (long)s * 1024;
    float s1 = 0.f, s2 = 0.f;
#pragma unroll
    for (int c = 0; c < 2; ++c) {
        const int d0 = (lane + c * 64) * 8;
        const bf16x8 v = *reinterpret_cast<const bf16x8*>(row + d0);
#pragma unroll
        for (int e = 0; e < 8; ++e) {
            const float f = (float)v[e];
            s1 += u[d0 + e] * f;
            s2 += w2[d0 + e] * f;
        }
    }
#pragma unroll
    for (int off = 32; off; off >>= 1) { s1 += __shfl_down(s1, off); s2 += __shfl_down(s2, off); }
    if (lane == 0) {
        RU[s] = SCALE * (s1 + cO[0]);
        RW[s] = SCALE * s2;
    }
}

// ---------------- K2d: MTb = bf16( SCALE * sum of 4 partials ) ----------------
__global__ __launch_bounds__(256)
void k_cvtS(const float* __restrict__ p, bf16_t* __restrict__ out) {
    const int i = blockIdx.x * 256 + threadIdx.x;
    const f32x4* rp = reinterpret_cast<const f32x4*>(p);
    const f32x4 a0 = rp[i], a1 = rp[i + 262144], a2 = rp[i + 524288], a3 = rp[i + 786432];
    bf16x4 o;
    o.x = (bf16_t)(SCALE * (a0.x + a1.x + a2.x + a3.x));
    o.y = (bf16_t)(SCALE * (a0.y + a1.y + a2.y + a3.y));
    o.z = (bf16_t)(SCALE * (a0.z + a1.z + a2.z + a3.z));
    o.w = (bf16_t)(SCALE * (a0.w + a1.w + a2.w + a3.w));
    reinterpret_cast<bf16x4*>(out)[i] = o;
}

// ========== main pipelined GEMM (R12 skeleton, BN=128/NF=2, dbuf BK=64) ==========
// MODE 0: t_s = xb @ MTb^T. Grid 512, m-grouped XCD chunks: XCD c owns m-panels
//         [8c,8c+8) x all 8 n -> per-XCD working set = 2MB A + 2MB B = 4MB (L2).
// MODE 1: out[z] = t_s[z] @ xb[z]^T + xb[z] @ wvb^T + RU[row] + RW[col] + bv[col]
//         (K=2048 dual source; NTT=32; grid 512, XCD = batch)
#define GLOAD(SRC, DST) __builtin_amdgcn_global_load_lds( \
    (const __attribute__((address_space(1))) uint32_t*)(SRC), \
    (__attribute__((address_space(3))) uint32_t*)(DST), 16, 0, 0)

template<int MODE>
__global__ __launch_bounds__(512, 2)
void k_db2(const bf16_t* __restrict__ A1, const bf16_t* __restrict__ A2,
           const bf16_t* __restrict__ B1, const bf16_t* __restrict__ B2,
           const float* __restrict__ RUv, const float* __restrict__ RWv,
           const float* __restrict__ bv,
           bf16_t* __restrict__ oT, float* __restrict__ oF)
{
    constexpr int SLOT = 32768;             // (128+128)*128 B
    constexpr int NTT  = (MODE == 0) ? 16 : 32;
    __shared__ __align__(16) unsigned char slds[2 * SLOT];

    const int tid  = threadIdx.x;
    const int wave = tid >> 6, lane = tid & 63;
    const int wm = wave >> 2, wn = wave & 3;
    const int llo = lane & 15, lhi = lane >> 4;

    int bm, bn, z = 0;
    const int nw = ((int)blockIdx.x & 7) * 64 + ((int)blockIdx.x >> 3);
    if (MODE == 0) {
        bm = (nw >> 3) * 128;               // m-grouped: XCD c -> m-panels [8c,8c+8)
        bn = (nw & 7) * 128;
    } else {
        z = nw >> 6;                        // batch = XCD
        const int r = nw & 63;
        bm = (r >> 3) * 128; bn = (r & 7) * 128;   // local within batch
    }
    const long zo = (long)z << 20;

    // staging geometry (proven swizzle: phys chunk = logical ^ (row&7))
    const bf16_t *sA1[2], *sB1[2], *sA2[2], *sB2[2];
    int dA[2], dB[2];
#pragma unroll
    for (int j = 0; j < 2; ++j) {
        const int C = j * 512 + tid;
        const int r = C >> 3, u = (C & 7) ^ (r & 7);
        const long aoff = (long)(bm + r) * 1024 + (u << 3);
        const long boff = (long)(bn + r) * 1024 + (u << 3);
        sA1[j] = A1 + zo + aoff;  dA[j] = C << 4;
        sB1[j] = B1 + zo + boff;  dB[j] = 16384 + (C << 4);
        if (MODE == 1) { sA2[j] = A2 + zo + aoff; sB2[j] = B2 + boff; }  // B2: no batch offset
    }

    auto stage = [&](int tt) {
        unsigned char* s = &slds[(tt & 1) * SLOT];
        const long ko = (long)(tt & 15) << 6;
        const bool hB = (MODE == 1) && (tt >= 16);
#pragma unroll
        for (int j = 0; j < 2; ++j) {
            GLOAD((hB ? sA2[j] : sA1[j]) + ko, s + dA[j]);
            GLOAD((hB ? sB2[j] : sB1[j]) + ko, s + dB[j]);
        }
    };

    f32x4 acc[4][2];
    const f32x4 fz = {0.f, 0.f, 0.f, 0.f};
#pragma unroll
    for (int i = 0; i < 4; ++i)
#pragma unroll
        for (int j = 0; j < 2; ++j) acc[i][j] = fz;

    stage(0);

    for (int t = 0; t < NTT; ++t) {
        if (t + 1 < NTT) {
            stage(t + 1);
            asm volatile("s_waitcnt vmcnt(4)" ::: "memory");
        } else {
            asm volatile("s_waitcnt vmcnt(0)" ::: "memory");
        }
        __builtin_amdgcn_s_barrier();

        const unsigned char* sb = &slds[(t & 1) * SLOT];
#pragma unroll
        for (int ks = 0; ks < 2; ++ks) {
            bf16x8 af[4], bfv[2];
#pragma unroll
            for (int mi = 0; mi < 4; ++mi) {
                const int r = wm * 64 + mi * 16 + llo;
                af[mi] = *reinterpret_cast<const bf16x8*>(
                    sb + r * 128 + ((((ks << 2) | lhi) ^ (r & 7)) << 4));
            }
#pragma unroll
            for (int ni = 0; ni < 2; ++ni) {
                const int r = wn * 32 + ni * 16 + llo;
                bfv[ni] = *reinterpret_cast<const bf16x8*>(
                    sb + 16384 + r * 128 + ((((ks << 2) | lhi) ^ (r & 7)) << 4));
            }
            __builtin_amdgcn_s_setprio(1);
#pragma unroll
            for (int mi = 0; mi < 4; ++mi)
#pragma unroll
                for (int ni = 0; ni < 2; ++ni)
                    acc[mi][ni] = __builtin_amdgcn_mfma_f32_16x16x32_bf16(
                        af[mi], bfv[ni], acc[mi][ni], 0, 0, 0);
            __builtin_amdgcn_s_setprio(0);
        }
        asm volatile("s_waitcnt lgkmcnt(0)" ::: "memory");
        __builtin_amdgcn_s_barrier();
    }

    // ---------------- epilogue ----------------
#pragma unroll
    for (int mi = 0; mi < 4; ++mi) {
        const int lr0 = bm + wm * 64 + mi * 16 + lhi * 4;
#pragma unroll
        for (int ni = 0; ni < 2; ++ni) {
            const int cg = bn + wn * 32 + ni * 16 + llo;
            const f32x4 v = acc[mi][ni];
            if (MODE == 0) {
#pragma unroll
                for (int j = 0; j < 4; ++j)
                    oT[(long)(lr0 + j) * 1024 + cg] = (bf16_t)v[j];
            } else {
                const float cterm = RWv[z * 1024 + cg] + bv[cg];
#pragma unroll
                for (int j = 0; j < 4; ++j) {
                    const int lr = lr0 + j;
                    oF[zo + (long)lr * 1024 + cg] = v[j] + RUv[z * 1024 + lr] + cterm;
                }
            }
        }
    }
}
#undef GLOAD

extern "C" void kernel_launch(void* const* d_in, const int* in_sizes, int n_in,
                              void* d_out, int out_size, void* d_ws, size_t ws_size,
                              hipStream_t stream) {
    const float* x    = (const float*)d_in[0];
    const float* Wqkv = (const float*)d_in[1];
    const float* bqkv = (const float*)d_in[2];
    const float* w    = (const float*)d_in[3];
    float* out = (float*)d_out;

    // workspace layout
    char* ws = (char*)d_ws;
    bf16_t* xb   = (bf16_t*)ws;                       // 16 MiB [prep -> end]
    float*  pbig = (float*) (ws + (16l << 20));       // 16 MiB: X1 partials, then MT partials
    bf16_t* tsb  = (bf16_t*)(ws + (16l << 20));       // 16 MiB: t_s (after partials dead)
    bf16_t* weff = (bf16_t*)(ws + (32l << 20));       // 2 MiB
    bf16_t* wtb  = (bf16_t*)(ws + (34l << 20));       // 2 MiB
    bf16_t* wqt  = (bf16_t*)(ws + (36l << 20));       // 2 MiB
    bf16_t* wkt  = (bf16_t*)(ws + (38l << 20));       // 2 MiB
    bf16_t* wvb  = (bf16_t*)(ws + (40l << 20));       // 2 MiB
    bf16_t* X1b  = (bf16_t*)(ws + (42l << 20));       // 2 MiB
    bf16_t* MTb  = (bf16_t*)(ws + (44l << 20));       // 2 MiB
    char*   sm   = ws + (46l << 20);
    float* h1 = (float*)sm;
    float* h2 = (float*)(sm + 4096);
    float* u  = (float*)(sm + 8192);
    float* w2 = (float*)(sm + 12288);
    float* cO = (float*)(sm + 16384);
    float* RU = (float*)(sm + 20480);                 // 32 KiB
    float* RW = (float*)(sm + 53248);                 // 32 KiB
    if (ws_size < (size_t)(54l << 20) + 65536) return;

    // K1: preamble (xb | wvb | weff+wtb | wqt | wkt)
    k_prep<<<12288, 256, 0, stream>>>(x, Wqkv, w, xb, wvb, weff, wtb, wqt, wkt);

    // K2a: X1 = Wk^T Weff^T (split-K partials) + h1,h2
    k_midA<<<768, 256, 0, stream>>>(wkt, weff, wtb, bqkv, pbig, h1, h2);

    // K2b: X1b = bf16(sum partials) + u,w2 + c
    k_cvtA<<<1537, 256, 0, stream>>>(pbig, X1b, wqt, wkt, h1, h2, bqkv, u, w2, cO);

    // K2c: MT = X1b Wq (split-K partials) + RU/RW GEMVs over xb
    k_midB<<<2304, 256, 0, stream>>>(X1b, wqt, pbig, xb, u, w2, cO, RU, RW);

    // K2d: MTb = bf16(SCALE * sum partials)
    k_cvtS<<<1024, 256, 0, stream>>>(pbig, MTb);

    // t_s = xb @ MTb^T  (512 blocks, m-grouped XCD chunks)
    k_db2<0><<<512, 512, 0, stream>>>(xb, nullptr, MTb, nullptr,
                                      nullptr, nullptr, nullptr, tsb, nullptr);

    // out = t_s@x^T + x@Wv^T + RU + RW + bv  (512 blocks, XCD = batch)
    k_db2<1><<<512, 512, 0, stream>>>(tsb, xb, xb, wvb,
                                      RU, RW, bqkv + 2048, nullptr, out);
}

// Round 17
// 107.681 us; speedup vs baseline: 1.0579x; 1.0050x over previous
//
#include <hip/hip_runtime.h>
#include <hip/hip_bf16.h>
#include <stdint.h>

typedef __bf16 bf16_t;
typedef __bf16 bf16x8 __attribute__((ext_vector_type(8)));
typedef __bf16 bf16x4 __attribute__((ext_vector_type(4)));
typedef float  f32x4  __attribute__((ext_vector_type(4)));

#define DIM   1024
#define BATCH 8
#define SCALE 0.03125f        /* 1/sqrt(1024) */

// Algebra: out[z,i,n] = v[z,i,n] + SCALE*scores[z,i,n]
//   scores = x M x^T + (x u)1^T + 1(w2^T x^T) + c,  M = Wq^T Weff Wk
//   MT = (Wk^T Weff^T) Wq; t_s = x MT^T; out = t_s x^T + x Wv^T + RU + RW + bv
//   RU[s] = SCALE*(x·u + c), RW[s] = SCALE*(x·w2)
//   u = wqt·h1, w2 = wkt·h2, h1 = weff·bk, h2 = wtb·bq, c = bq·h1

// ---------------- wave row-dot helper ----------------
__device__ __forceinline__ float rowdot_bf16(const bf16_t* __restrict__ row,
                                             const float* __restrict__ vec, int lane) {
    float s = 0.f;
#pragma unroll
    for (int c = 0; c < 2; ++c) {
        const int d0 = (lane + c * 64) * 8;
        const bf16x8 v = *reinterpret_cast<const bf16x8*>(row + d0);
#pragma unroll
        for (int e = 0; e < 8; ++e) s += vec[d0 + e] * (float)v[e];
    }
#pragma unroll
    for (int off = 32; off; off >>= 1) s += __shfl_down(s, off);
    return s;   // valid in lane 0
}

// ---------------- f32x4 -> bf16x4 convert helper ----------------
__device__ __forceinline__ void cvt4(const float* __restrict__ in,
                                     bf16_t* __restrict__ out, int i) {
    const float4 v = reinterpret_cast<const float4*>(in)[i];
    bf16x4 o;
    o.x = (bf16_t)v.x; o.y = (bf16_t)v.y; o.z = (bf16_t)v.z; o.w = (bf16_t)v.w;
    reinterpret_cast<bf16x4*>(out)[i] = o;
}

// ------------- split-K 128x128 GEMM body (R12 proven, verbatim) -------------
__device__ __forceinline__ void gemm_sk(const bf16_t* __restrict__ A, const bf16_t* __restrict__ B,
                                        float* __restrict__ oP, int s, int tid,
                                        bf16_t* As, bf16_t* Bs)
{
    const int wave = tid >> 6, lane = tid & 63;
    const int bm = (s >> 5) * 128;
    const int bn = ((s >> 2) & 7) * 128;
    const int kb = (s & 3) * 256;
    float* outP  = oP + (long)(s & 3) * 1048576;
    const int wr = wave >> 1, wc = wave & 1;
    const int lhi = lane >> 4, llo = lane & 15;

    f32x4 acc[4][4];
    const f32x4 fz = {0.f, 0.f, 0.f, 0.f};
#pragma unroll
    for (int i = 0; i < 4; ++i)
#pragma unroll
        for (int j = 0; j < 4; ++j) acc[i][j] = fz;

    for (int k0 = 0; k0 < 256; k0 += 32) {
#pragma unroll
        for (int i = 0; i < 2; ++i) {
            const int c  = wave * 128 + i * 64 + lane;
            const int r  = c >> 2;
            const int cc = (c & 3) << 3;
            const long ga = (long)(bm + r) * 1024 + kb + k0 + cc;
            const long gb = (long)(bn + r) * 1024 + kb + k0 + cc;
            const int lbase = (wave * 128 + i * 64) << 3;
            __builtin_amdgcn_global_load_lds(
                (const __attribute__((address_space(1))) uint32_t*)(A + ga),
                (__attribute__((address_space(3))) uint32_t*)(&As[lbase]), 16, 0, 0);
            __builtin_amdgcn_global_load_lds(
                (const __attribute__((address_space(1))) uint32_t*)(B + gb),
                (__attribute__((address_space(3))) uint32_t*)(&Bs[lbase]), 16, 0, 0);
        }
        __syncthreads();

        bf16x8 af[4], bfr[4];
#pragma unroll
        for (int mi = 0; mi < 4; ++mi)
            af[mi] = *reinterpret_cast<const bf16x8*>(&As[(wr * 64 + mi * 16 + llo) * 32 + lhi * 8]);
#pragma unroll
        for (int ni = 0; ni < 4; ++ni)
            bfr[ni] = *reinterpret_cast<const bf16x8*>(&Bs[(wc * 64 + ni * 16 + llo) * 32 + lhi * 8]);
#pragma unroll
        for (int mi = 0; mi < 4; ++mi)
#pragma unroll
            for (int ni = 0; ni < 4; ++ni)
                acc[mi][ni] = __builtin_amdgcn_mfma_f32_16x16x32_bf16(af[mi], bfr[ni], acc[mi][ni], 0, 0, 0);
        __syncthreads();
    }

#pragma unroll
    for (int mi = 0; mi < 4; ++mi) {
        const int r0 = bm + wr * 64 + mi * 16 + lhi * 4;
#pragma unroll
        for (int ni = 0; ni < 4; ++ni) {
            const int cg = bn + wc * 64 + ni * 16 + llo;
            const f32x4 v = acc[mi][ni];
#pragma unroll
            for (int j = 0; j < 4; ++j)
                outP[(long)(r0 + j) * 1024 + cg] = v[j];
        }
    }
}

// ============== K1: weight preamble only (3072 blocks) ==============
// [0,1024):    weff[d][e] = bf16(sum_n w[n][d][e])  AND  wtb = weff^T
// [1024,2048): wqt = transpose of Wqkv rows 0..1023
// [2048,3072): wkt = transpose of Wqkv rows 1024..2047
__global__ __launch_bounds__(256)
void k_prep(const float* __restrict__ Wqkv, const float* __restrict__ w,
            bf16_t* __restrict__ weff, bf16_t* __restrict__ wtb,
            bf16_t* __restrict__ wqt, bf16_t* __restrict__ wkt)
{
    __shared__ float tile[32][33];
    const int b = blockIdx.x;
    if (b < 1024) {
        const int t  = b;
        const int tx = threadIdx.x & 31, ty = threadIdx.x >> 5;
        const int d0 = (t & 31) * 32, e0 = (t >> 5) * 32;
#pragma unroll
        for (int r = 0; r < 4; ++r) {
            const int d = d0 + r * 8 + ty;
            const int e = e0 + tx;
            const float sum =
                w[d * 1024 + e] + w[1048576 + d * 1024 + e] + w[2097152 + d * 1024 + e];
            tile[r * 8 + ty][tx] = sum;
            weff[(long)d * 1024 + e] = (bf16_t)sum;
        }
        __syncthreads();
#pragma unroll
        for (int r = 0; r < 4; ++r) {
            const int e = e0 + r * 8 + ty;
            const int d = d0 + tx;
            wtb[(long)e * 1024 + d] = (bf16_t)tile[tx][r * 8 + ty];
        }
    } else {
        const bool isQ = (b < 2048);
        const int t  = b - (isQ ? 1024 : 2048);
        const float* src = isQ ? Wqkv : (Wqkv + 1048576);
        bf16_t* dst = isQ ? wqt : wkt;
        const int tx = threadIdx.x & 31, ty = threadIdx.x >> 5;
        const int e0 = (t & 31) * 32, d0 = (t >> 5) * 32;
#pragma unroll
        for (int r = 0; r < 4; ++r)
            tile[r * 8 + ty][tx] = src[(long)(e0 + r * 8 + ty) * 1024 + d0 + tx];
        __syncthreads();
#pragma unroll
        for (int r = 0; r < 4; ++r)
            dst[(long)(d0 + r * 8 + ty) * 1024 + e0 + tx] = (bf16_t)tile[tx][r * 8 + ty];
    }
}

// ====== K2a (8960 blocks): X1-GEMM ∪ h1,h2 rowdots ∪ x-cvt (overlapped) ======
// [0,256):    X1 = Wk^T Weff^T split-K partials
// [256,768):  h1 = Weff*bk, h2 = Weff^T*bq
// [768,8960): xb = bf16(x)  (memory-bound; overlaps the GEMM compute)
__global__ __launch_bounds__(256)
void k_midA(const bf16_t* __restrict__ wkt, const bf16_t* __restrict__ weff,
            const bf16_t* __restrict__ wtb, const float* __restrict__ bqkv,
            const float* __restrict__ x, bf16_t* __restrict__ xb,
            float* __restrict__ pX1, float* __restrict__ h1, float* __restrict__ h2)
{
    __shared__ __align__(16) bf16_t As[128 * 32];
    __shared__ __align__(16) bf16_t Bs[128 * 32];
    const int b = blockIdx.x;
    if (b < 256) {
        gemm_sk(wkt, weff, pX1, b, threadIdx.x, As, Bs);
        return;
    }
    if (b < 768) {
        const int wave = threadIdx.x >> 6, lane = threadIdx.x & 63;
        const int r = (b - 256) * 4 + wave;              // 0..2047
        if (r < 1024) {
            const float s = rowdot_bf16(weff + (long)r * 1024, bqkv + 1024, lane);
            if (lane == 0) h1[r] = s;
        } else {
            const float s = rowdot_bf16(wtb + (long)(r - 1024) * 1024, bqkv, lane);
            if (lane == 0) h2[r - 1024] = s;
        }
        return;
    }
    cvt4(x, xb, (b - 768) * 256 + threadIdx.x);          // 2097152 f32x4 total
}

// ====== K2b: X1b = bf16(sum4 partials) ∪ u,w2 row-dots ∪ c ======
__global__ __launch_bounds__(256)
void k_cvtA(const float* __restrict__ p, bf16_t* __restrict__ X1b,
            const bf16_t* __restrict__ wqt, const bf16_t* __restrict__ wkt,
            const float* __restrict__ h1, const float* __restrict__ h2,
            const float* __restrict__ bqkv,
            float* __restrict__ u, float* __restrict__ w2, float* __restrict__ cO)
{
    const int b = blockIdx.x;
    if (b < 1024) {
        const int i = b * 256 + threadIdx.x;
        const f32x4* rp = reinterpret_cast<const f32x4*>(p);
        const f32x4 a0 = rp[i], a1 = rp[i + 262144], a2 = rp[i + 524288], a3 = rp[i + 786432];
        bf16x4 o;
        o.x = (bf16_t)(a0.x + a1.x + a2.x + a3.x);
        o.y = (bf16_t)(a0.y + a1.y + a2.y + a3.y);
        o.z = (bf16_t)(a0.z + a1.z + a2.z + a3.z);
        o.w = (bf16_t)(a0.w + a1.w + a2.w + a3.w);
        reinterpret_cast<bf16x4*>(X1b)[i] = o;
    } else if (b < 1536) {
        const int wave = threadIdx.x >> 6, lane = threadIdx.x & 63;
        const int rr = (b - 1024) * 4 + wave;            // 0..2047
        if (rr < 1024) {
            const float s = rowdot_bf16(wqt + (long)rr * 1024, h1, lane);
            if (lane == 0) u[rr] = s;
        } else {
            const float s = rowdot_bf16(wkt + (long)(rr - 1024) * 1024, h2, lane);
            if (lane == 0) w2[rr - 1024] = s;
        }
    } else {
        if (threadIdx.x < 64) {
            float s = 0.f;
            for (int i = threadIdx.x; i < 1024; i += 64) s += bqkv[i] * h1[i];
#pragma unroll
            for (int off = 32; off; off >>= 1) s += __shfl_down(s, off);
            if (threadIdx.x == 0) cO[0] = s;             // c = bq . h1
        }
    }
}

// ====== K2c (3328 blocks): MT-GEMM ∪ RU/RW GEMV ∪ wvb-cvt (overlapped) ======
// [0,256):     MT = X1b Wq split-K partials
// [256,2304):  RU[s] = SCALE*(x·u + c), RW[s] = SCALE*(x·w2)  (s = (b-256)*4+wave)
// [2304,3328): wvb = bf16(Wqkv rows 2048..3071)
__global__ __launch_bounds__(256)
void k_midB(const bf16_t* __restrict__ X1b, const bf16_t* __restrict__ wqt,
            float* __restrict__ pMT, const bf16_t* __restrict__ xb,
            const float* __restrict__ u, const float* __restrict__ w2,
            const float* __restrict__ cO, const float* __restrict__ Wqkv,
            bf16_t* __restrict__ wvb,
            float* __restrict__ RU, float* __restrict__ RW)
{
    __shared__ __align__(16) bf16_t As[128 * 32];
    __shared__ __align__(16) bf16_t Bs[128 * 32];
    const int b = blockIdx.x;
    if (b < 256) {
        gemm_sk(X1b, wqt, pMT, b, threadIdx.x, As, Bs);
        return;
    }
    if (b < 2304) {
        const int wave = threadIdx.x >> 6, lane = threadIdx.x & 63;
        const int s = (b - 256) * 4 + wave;              // 0..8191
        const bf16_t* row = xb + (long)s * 1024;
        float s1 = 0.f, s2 = 0.f;
#pragma unroll
        for (int c = 0; c < 2; ++c) {
            const int d0 = (lane + c * 64) * 8;
            const bf16x8 v = *reinterpret_cast<const bf16x8*>(row + d0);
#pragma unroll
            for (int e = 0; e < 8; ++e) {
                const float f = (float)v[e];
                s1 += u[d0 + e] * f;
                s2 += w2[d0 + e] * f;
            }
        }
#pragma unroll
        for (int off = 32; off; off >>= 1) { s1 += __shfl_down(s1, off); s2 += __shfl_down(s2, off); }
        if (lane == 0) {
            RU[s] = SCALE * (s1 + cO[0]);
            RW[s] = SCALE * s2;
        }
        return;
    }
    cvt4(Wqkv + 2097152, wvb, (b - 2304) * 256 + threadIdx.x);   // 262144 f32x4
}

// ---------------- K2d: MTb = bf16( SCALE * sum of 4 partials ) ----------------
__global__ __launch_bounds__(256)
void k_cvtS(const float* __restrict__ p, bf16_t* __restrict__ out) {
    const int i = blockIdx.x * 256 + threadIdx.x;
    const f32x4* rp = reinterpret_cast<const f32x4*>(p);
    const f32x4 a0 = rp[i], a1 = rp[i + 262144], a2 = rp[i + 524288], a3 = rp[i + 786432];
    bf16x4 o;
    o.x = (bf16_t)(SCALE * (a0.x + a1.x + a2.x + a3.x));
    o.y = (bf16_t)(SCALE * (a0.y + a1.y + a2.y + a3.y));
    o.z = (bf16_t)(SCALE * (a0.z + a1.z + a2.z + a3.z));
    o.w = (bf16_t)(SCALE * (a0.w + a1.w + a2.w + a3.w));
    reinterpret_cast<bf16x4*>(out)[i] = o;
}

// ========== main pipelined GEMM (R14/R16-proven, verbatim) ==========
// MODE 0: t_s = xb @ MTb^T. Grid 512, m-grouped XCD chunks (4MB/XCD L2-resident).
// MODE 1: out[z] = t_s[z] @ xb[z]^T + xb[z] @ wvb^T + RU[row] + RW[col] + bv[col]
//         (K=2048 dual source; NTT=32; grid 512, XCD = batch)
#define GLOAD(SRC, DST) __builtin_amdgcn_global_load_lds( \
    (const __attribute__((address_space(1))) uint32_t*)(SRC), \
    (__attribute__((address_space(3))) uint32_t*)(DST), 16, 0, 0)

template<int MODE>
__global__ __launch_bounds__(512, 2)
void k_db2(const bf16_t* __restrict__ A1, const bf16_t* __restrict__ A2,
           const bf16_t* __restrict__ B1, const bf16_t* __restrict__ B2,
           const float* __restrict__ RUv, const float* __restrict__ RWv,
           const float* __restrict__ bv,
           bf16_t* __restrict__ oT, float* __restrict__ oF)
{
    constexpr int SLOT = 32768;             // (128+128)*128 B
    constexpr int NTT  = (MODE == 0) ? 16 : 32;
    __shared__ __align__(16) unsigned char slds[2 * SLOT];

    const int tid  = threadIdx.x;
    const int wave = tid >> 6, lane = tid & 63;
    const int wm = wave >> 2, wn = wave & 3;
    const int llo = lane & 15, lhi = lane >> 4;

    int bm, bn, z = 0;
    const int nw = ((int)blockIdx.x & 7) * 64 + ((int)blockIdx.x >> 3);
    if (MODE == 0) {
        bm = (nw >> 3) * 128;               // m-grouped: XCD c -> m-panels [8c,8c+8)
        bn = (nw & 7) * 128;
    } else {
        z = nw >> 6;                        // batch = XCD
        const int r = nw & 63;
        bm = (r >> 3) * 128; bn = (r & 7) * 128;   // local within batch
    }
    const long zo = (long)z << 20;

    // staging geometry (proven swizzle: phys chunk = logical ^ (row&7))
    const bf16_t *sA1[2], *sB1[2], *sA2[2], *sB2[2];
    int dA[2], dB[2];
#pragma unroll
    for (int j = 0; j < 2; ++j) {
        const int C = j * 512 + tid;
        const int r = C >> 3, u = (C & 7) ^ (r & 7);
        const long aoff = (long)(bm + r) * 1024 + (u << 3);
        const long boff = (long)(bn + r) * 1024 + (u << 3);
        sA1[j] = A1 + zo + aoff;  dA[j] = C << 4;
        sB1[j] = B1 + zo + boff;  dB[j] = 16384 + (C << 4);
        if (MODE == 1) { sA2[j] = A2 + zo + aoff; sB2[j] = B2 + boff; }  // B2: no batch offset
    }

    auto stage = [&](int tt) {
        unsigned char* s = &slds[(tt & 1) * SLOT];
        const long ko = (long)(tt & 15) << 6;
        const bool hB = (MODE == 1) && (tt >= 16);
#pragma unroll
        for (int j = 0; j < 2; ++j) {
            GLOAD((hB ? sA2[j] : sA1[j]) + ko, s + dA[j]);
            GLOAD((hB ? sB2[j] : sB1[j]) + ko, s + dB[j]);
        }
    };

    f32x4 acc[4][2];
    const f32x4 fz = {0.f, 0.f, 0.f, 0.f};
#pragma unroll
    for (int i = 0; i < 4; ++i)
#pragma unroll
        for (int j = 0; j < 2; ++j) acc[i][j] = fz;

    stage(0);

    for (int t = 0; t < NTT; ++t) {
        if (t + 1 < NTT) {
            stage(t + 1);
            asm volatile("s_waitcnt vmcnt(4)" ::: "memory");
        } else {
            asm volatile("s_waitcnt vmcnt(0)" ::: "memory");
        }
        __builtin_amdgcn_s_barrier();

        const unsigned char* sb = &slds[(t & 1) * SLOT];
#pragma unroll
        for (int ks = 0; ks < 2; ++ks) {
            bf16x8 af[4], bfv[2];
#pragma unroll
            for (int mi = 0; mi < 4; ++mi) {
                const int r = wm * 64 + mi * 16 + llo;
                af[mi] = *reinterpret_cast<const bf16x8*>(
                    sb + r * 128 + ((((ks << 2) | lhi) ^ (r & 7)) << 4));
            }
#pragma unroll
            for (int ni = 0; ni < 2; ++ni) {
                const int r = wn * 32 + ni * 16 + llo;
                bfv[ni] = *reinterpret_cast<const bf16x8*>(
                    sb + 16384 + r * 128 + ((((ks << 2) | lhi) ^ (r & 7)) << 4));
            }
            __builtin_amdgcn_s_setprio(1);
#pragma unroll
            for (int mi = 0; mi < 4; ++mi)
#pragma unroll
                for (int ni = 0; ni < 2; ++ni)
                    acc[mi][ni] = __builtin_amdgcn_mfma_f32_16x16x32_bf16(
                        af[mi], bfv[ni], acc[mi][ni], 0, 0, 0);
            __builtin_amdgcn_s_setprio(0);
        }
        asm volatile("s_waitcnt lgkmcnt(0)" ::: "memory");
        __builtin_amdgcn_s_barrier();
    }

    // ---------------- epilogue ----------------
#pragma unroll
    for (int mi = 0; mi < 4; ++mi) {
        const int lr0 = bm + wm * 64 + mi * 16 + lhi * 4;
#pragma unroll
        for (int ni = 0; ni < 2; ++ni) {
            const int cg = bn + wn * 32 + ni * 16 + llo;
            const f32x4 v = acc[mi][ni];
            if (MODE == 0) {
#pragma unroll
                for (int j = 0; j < 4; ++j)
                    oT[(long)(lr0 + j) * 1024 + cg] = (bf16_t)v[j];
            } else {
                const float cterm = RWv[z * 1024 + cg] + bv[cg];
#pragma unroll
                for (int j = 0; j < 4; ++j) {
                    const int lr = lr0 + j;
                    oF[zo + (long)lr * 1024 + cg] = v[j] + RUv[z * 1024 + lr] + cterm;
                }
            }
        }
    }
}
#undef GLOAD

extern "C" void kernel_launch(void* const* d_in, const int* in_sizes, int n_in,
                              void* d_out, int out_size, void* d_ws, size_t ws_size,
                              hipStream_t stream) {
    const float* x    = (const float*)d_in[0];
    const float* Wqkv = (const float*)d_in[1];
    const float* bqkv = (const float*)d_in[2];
    const float* w    = (const float*)d_in[3];
    float* out = (float*)d_out;

    // workspace layout
    char* ws = (char*)d_ws;
    bf16_t* xb   = (bf16_t*)ws;                       // 16 MiB
    float*  pbig = (float*) (ws + (16l << 20));       // 16 MiB: X1 partials, then MT partials
    bf16_t* tsb  = (bf16_t*)(ws + (16l << 20));       // 16 MiB: t_s (after partials dead)
    bf16_t* weff = (bf16_t*)(ws + (32l << 20));       // 2 MiB
    bf16_t* wtb  = (bf16_t*)(ws + (34l << 20));       // 2 MiB
    bf16_t* wqt  = (bf16_t*)(ws + (36l << 20));       // 2 MiB
    bf16_t* wkt  = (bf16_t*)(ws + (38l << 20));       // 2 MiB
    bf16_t* wvb  = (bf16_t*)(ws + (40l << 20));       // 2 MiB
    bf16_t* X1b  = (bf16_t*)(ws + (42l << 20));       // 2 MiB
    bf16_t* MTb  = (bf16_t*)(ws + (44l << 20));       // 2 MiB
    char*   sm   = ws + (46l << 20);
    float* h1 = (float*)sm;
    float* h2 = (float*)(sm + 4096);
    float* u  = (float*)(sm + 8192);
    float* w2 = (float*)(sm + 12288);
    float* cO = (float*)(sm + 16384);
    float* RU = (float*)(sm + 20480);                 // 32 KiB
    float* RW = (float*)(sm + 53248);                 // 32 KiB
    if (ws_size < (size_t)(54l << 20) + 65536) return;

    // K1: weight preamble (weff+wtb | wqt | wkt)
    k_prep<<<3072, 256, 0, stream>>>(Wqkv, w, weff, wtb, wqt, wkt);

    // K2a: X1 GEMM + h1,h2 + x-cvt (memory/compute overlapped)
    k_midA<<<8960, 256, 0, stream>>>(wkt, weff, wtb, bqkv, x, xb, pbig, h1, h2);

    // K2b: X1b = bf16(sum partials) + u,w2 + c
    k_cvtA<<<1537, 256, 0, stream>>>(pbig, X1b, wqt, wkt, h1, h2, bqkv, u, w2, cO);

    // K2c: MT GEMM + RU/RW GEMVs + wvb-cvt (overlapped)
    k_midB<<<3328, 256, 0, stream>>>(X1b, wqt, pbig, xb, u, w2, cO, Wqkv, wvb, RU, RW);

    // K2d: MTb = bf16(SCALE * sum partials)
    k_cvtS<<<1024, 256, 0, stream>>>(pbig, MTb);

    // t_s = xb @ MTb^T  (512 blocks, m-grouped XCD chunks)
    k_db2<0><<<512, 512, 0, stream>>>(xb, nullptr, MTb, nullptr,
                                      nullptr, nullptr, nullptr, tsb, nullptr);

    // out = t_s@x^T + x@Wv^T + RU + RW + bv  (512 blocks, XCD = batch)
    k_db2<1><<<512, 512, 0, stream>>>(tsb, xb, xb, wvb,
                                      RU, RW, bqkv + 2048, nullptr, out);
}